// Round 1
// baseline (1201.115 us; speedup 1.0000x reference)
//
#include <hip/hip_runtime.h>
#include <math.h>

// ---------- common types / helpers ----------
typedef __bf16 bf16x8 __attribute__((ext_vector_type(8)));
typedef float f32x4 __attribute__((ext_vector_type(4)));

#define LOG2E 1.4426950408889634f

__device__ __forceinline__ unsigned short bf16r(float f) {
  unsigned u = __float_as_uint(f);
  u = (u + 0x7fffu + ((u >> 16) & 1u)) >> 16;
  return (unsigned short)u;
}
__device__ __forceinline__ float bf2f(unsigned short h) {
  return __uint_as_float(((unsigned)h) << 16);
}

// ---------- elementwise conversion kernels ----------
__global__ void convk(const float* __restrict__ in, unsigned short* __restrict__ out, long n) {
  long i = ((long)blockIdx.x * 256 + threadIdx.x) * 4;
  if (i >= n) return;
  float4 v = *(const float4*)&in[i];
  ushort4 o;
  o.x = bf16r(v.x); o.y = bf16r(v.y); o.z = bf16r(v.z); o.w = bf16r(v.w);
  *(ushort4*)&out[i] = o;
}

// wkv_a (576x2048) -> bf16 padded to 640 rows (zeros) so GEMM loads are in-bounds
__global__ void conv_wab(const float* __restrict__ in, unsigned short* __restrict__ out) {
  long i = ((long)blockIdx.x * 256 + threadIdx.x) * 4;
  if (i >= 640L * 2048) return;
  long row = i >> 11;
  ushort4 o;
  if (row < 576) {
    float4 v = *(const float4*)&in[i];
    o.x = bf16r(v.x); o.y = bf16r(v.y); o.z = bf16r(v.z); o.w = bf16r(v.w);
  } else {
    o.x = o.y = o.z = o.w = 0;
  }
  *(ushort4*)&out[i] = o;
}

// wkT[h][c][d] = wkv_b[(h*256+d)*512 + c]  (transposed wk so GEMM-BT applies)
__global__ void make_wkT(const float* __restrict__ wkvb, unsigned short* __restrict__ wkT) {
  long idx = (long)blockIdx.x * 256 + threadIdx.x;  // < 16*512*128
  int d = (int)(idx & 127);
  int c = (int)((idx >> 7) & 511);
  int h = (int)(idx >> 16);
  wkT[idx] = bf16r(wkvb[((long)(h * 256 + d)) * 512 + c]);
}

// ---------- generic 128x128 bf16 GEMM:  C = alpha * A(MxK) * B(NxK)^T ----------
// A,B bf16 row-major (B already transposed = [N][K]); C f32 or bf16.
// LDS padded to 40 elems/row => ds_read bank-conflict free. Batched via blockIdx.z.
template <int OUT_BF16>
__global__ __launch_bounds__(256) void gemm_bt(
    const unsigned short* __restrict__ A, const unsigned short* __restrict__ B,
    void* __restrict__ Cv, int M, int Nstore, int K, int lda, int ldb, int ldc,
    long sA, long sB, long sC, float alpha)
{
  __shared__ unsigned short As[128 * 40];
  __shared__ unsigned short Bs[128 * 40];
  const int tid = threadIdx.x;
  const int w = tid >> 6, l = tid & 63, lg = l & 15, lh = l >> 4;
  const long bz = blockIdx.z;
  const unsigned short* Ab = A + bz * sA + (long)(blockIdx.x * 128) * lda;
  const unsigned short* Bb = B + bz * sB + (long)(blockIdx.y * 128) * ldb;
  const int sr = tid >> 2;          // 0..63
  const int sc = (tid & 3) * 8;     // 0,8,16,24
  const int wm = (w >> 1) * 64, wn = (w & 1) * 64;
  f32x4 acc[4][4] = {};

  for (int k0 = 0; k0 < K; k0 += 32) {
    uint4 a0 = *(const uint4*)&Ab[(long)sr * lda + k0 + sc];
    uint4 a1 = *(const uint4*)&Ab[(long)(sr + 64) * lda + k0 + sc];
    uint4 b0 = *(const uint4*)&Bb[(long)sr * ldb + k0 + sc];
    uint4 b1 = *(const uint4*)&Bb[(long)(sr + 64) * ldb + k0 + sc];
    __syncthreads();   // previous iteration's LDS reads done
    *(uint4*)&As[sr * 40 + sc] = a0;
    *(uint4*)&As[(sr + 64) * 40 + sc] = a1;
    *(uint4*)&Bs[sr * 40 + sc] = b0;
    *(uint4*)&Bs[(sr + 64) * 40 + sc] = b1;
    __syncthreads();
    bf16x8 af[4], bfr[4];
#pragma unroll
    for (int m = 0; m < 4; m++) af[m] = *(const bf16x8*)&As[(wm + m * 16 + lg) * 40 + lh * 8];
#pragma unroll
    for (int n = 0; n < 4; n++) bfr[n] = *(const bf16x8*)&Bs[(wn + n * 16 + lg) * 40 + lh * 8];
#pragma unroll
    for (int m = 0; m < 4; m++)
#pragma unroll
      for (int n = 0; n < 4; n++)
        acc[m][n] = __builtin_amdgcn_mfma_f32_16x16x32_bf16(af[m], bfr[n], acc[m][n], 0, 0, 0);
  }

  const int row0 = blockIdx.x * 128 + wm, col0 = blockIdx.y * 128 + wn;
#pragma unroll
  for (int m = 0; m < 4; m++)
#pragma unroll
    for (int n = 0; n < 4; n++)
#pragma unroll
      for (int r = 0; r < 4; r++) {
        int row = row0 + m * 16 + lh * 4 + r;
        int col = col0 + n * 16 + lg;
        if (col < Nstore) {
          float v = acc[m][n][r] * alpha;
          if (OUT_BF16)
            ((unsigned short*)Cv)[bz * sC + (long)row * ldc + col] = bf16r(v);
          else
            ((float*)Cv)[bz * sC + (long)row * ldc + col] = v;
        }
      }
}

// ---------- kv epilogue: tanh-norm + rope -> k_lat bf16 [B*S][576] ----------
__global__ void kv_epilogue(const float* __restrict__ kvf, const float* __restrict__ fc,
                            const float* __restrict__ fs, const float* __restrict__ alpha,
                            const float* __restrict__ gamma, const float* __restrict__ beta,
                            unsigned short* __restrict__ k_lat) {
  const int n = blockIdx.x;          // b*2048 + s
  const int s = n & 2047;
  const int tid = threadIdx.x;
  const float a = alpha[0];
  const float* src = kvf + (long)n * 576;
  unsigned short* dst = k_lat + (long)n * 576;
  for (int c = tid; c < 512; c += 256) {
    float v = tanhf(a * src[c]) * gamma[c] + beta[c];
    dst[c] = bf16r(v);
  }
  if (tid < 32) {
    int i = tid;
    float re = src[512 + 2 * i], im = src[512 + 2 * i + 1];
    float co = fc[s * 32 + i], si = fs[s * 32 + i];
    dst[512 + 2 * i] = bf16r(re * co - im * si);
    dst[512 + 2 * i + 1] = bf16r(re * si + im * co);
  }
}

// ---------- transpose kvn -> vt[b][c(512)][s(2048)] ----------
__global__ void transpose_v(const unsigned short* __restrict__ k_lat, unsigned short* __restrict__ vt) {
  __shared__ unsigned short t[32][33];
  const int b = blockIdx.z;
  const int s0 = blockIdx.x * 32, c0 = blockIdx.y * 32;
  const int tx = threadIdx.x, ty = threadIdx.y;   // (32,8)
#pragma unroll
  for (int i = 0; i < 4; i++)
    t[ty * 4 + i][tx] = k_lat[((long)b * 2048 + s0 + ty * 4 + i) * 576 + c0 + tx];
  __syncthreads();
#pragma unroll
  for (int i = 0; i < 4; i++)
    vt[((long)b * 512 + c0 + ty * 4 + i) * 2048 + s0 + tx] = t[tx][ty * 4 + i];
}

// ---------- q rope: q_b pe-part -> q_lat[...][512..576) (scaled) ----------
__global__ void q_rope(const unsigned short* __restrict__ q_b, const float* __restrict__ fc,
                       const float* __restrict__ fs, unsigned short* __restrict__ q_lat, float scale) {
  long idx = (long)blockIdx.x * 256 + threadIdx.x;   // < B*S*H*32
  int i = (int)(idx & 31);
  int h = (int)((idx >> 5) & 15);
  long n = idx >> 9;                 // b*2048+s
  int s = (int)(n & 2047);
  float re = bf2f(q_b[n * 3072 + h * 192 + 128 + 2 * i]);
  float im = bf2f(q_b[n * 3072 + h * 192 + 128 + 2 * i + 1]);
  float co = fc[s * 32 + i], si = fs[s * 32 + i];
  unsigned short* dst = q_lat + (n * 16 + h) * 576 + 512;
  dst[2 * i] = bf16r((re * co - im * si) * scale);
  dst[2 * i + 1] = bf16r((re * si + im * co) * scale);
}

// ---------- flash attention over latent space ----------
// Q rows = (b, s, h) flattened: [B][32768][576]; K = k_lat [B][2048][576];
// V = vt [B][512][2048] (transposed kvn). Non-causal. Out: o_lat [B][32768][512] bf16.
// 64 rows/block, 8 waves. QK: wave=(key-group kg=w>>1 of 32 keys, row-half rh=w&1).
// PV: wave w owns output cols [w*64, w*64+64). Softmax stats shared via LDS.
__global__ __launch_bounds__(512) void attn_kernel(
    const unsigned short* __restrict__ q_lat, const unsigned short* __restrict__ k_lat,
    const unsigned short* __restrict__ vt, unsigned short* __restrict__ o_lat)
{
  __shared__ unsigned short Qs[64 * 584];   // padded rows: conflict-free ds_read
  __shared__ unsigned short Ps[64 * 136];
  __shared__ float pmax[4][64];
  __shared__ float psum[4][64];
  __shared__ float mnew_s[64], fact_s[64], mrun[64], lrun[64];

  const int tid = threadIdx.x;
  const int w = tid >> 6, l = tid & 63, lg = l & 15, lh = l >> 4;
  const int b = blockIdx.x >> 9;
  const int row0 = (blockIdx.x & 511) * 64;
  const unsigned short* Qg = q_lat + ((long)b * 32768 + row0) * 576;
  const unsigned short* Kg = k_lat + (long)b * 2048 * 576;
  const unsigned short* Vg = vt + (long)b * 512 * 2048;

  for (int e = tid * 8; e < 64 * 576; e += 512 * 8) {
    int r = e / 576, c = e - r * 576;
    *(uint4*)&Qs[r * 584 + c] = *(const uint4*)&Qg[e];
  }
  if (tid < 64) { mrun[tid] = -1e30f; lrun[tid] = 0.f; }
  __syncthreads();

  const int kg = w >> 1, rh = w & 1;
  f32x4 acc_o[4][4] = {};

  for (int k0 = 0; k0 < 2048; k0 += 128) {
    // ---- QK: S slice [32 rows x 32 keys] ----
    f32x4 s00 = {}, s01 = {}, s10 = {}, s11 = {};
    const int kk0 = k0 + kg * 32;
    const unsigned short* Kr0 = Kg + (long)(kk0 + lg) * 576 + lh * 8;
    const unsigned short* Kr1 = Kr0 + 16 * 576;
    const unsigned short* Q0 = &Qs[(rh * 32 + lg) * 584 + lh * 8];
    const unsigned short* Q1 = Q0 + 16 * 584;
#pragma unroll 6
    for (int dd = 0; dd < 18; dd++) {
      const int d0 = dd * 32;
      bf16x8 a0 = *(const bf16x8*)(Q0 + d0);
      bf16x8 a1 = *(const bf16x8*)(Q1 + d0);
      bf16x8 kf0 = *(const bf16x8*)(Kr0 + d0);
      bf16x8 kf1 = *(const bf16x8*)(Kr1 + d0);
      s00 = __builtin_amdgcn_mfma_f32_16x16x32_bf16(a0, kf0, s00, 0, 0, 0);
      s01 = __builtin_amdgcn_mfma_f32_16x16x32_bf16(a0, kf1, s01, 0, 0, 0);
      s10 = __builtin_amdgcn_mfma_f32_16x16x32_bf16(a1, kf0, s10, 0, 0, 0);
      s11 = __builtin_amdgcn_mfma_f32_16x16x32_bf16(a1, kf1, s11, 0, 0, 0);
    }
    // ---- per-row slice max (reduce over 16 lanes = 16 key-cols, 2 n-subtiles) ----
    float mx[8];
#pragma unroll
    for (int r = 0; r < 4; r++) {
      mx[r] = fmaxf(s00[r], s01[r]);
      mx[4 + r] = fmaxf(s10[r], s11[r]);
    }
#pragma unroll
    for (int i = 0; i < 8; i++)
#pragma unroll
      for (int msk = 1; msk < 16; msk <<= 1)
        mx[i] = fmaxf(mx[i], __shfl_xor(mx[i], msk));
    if (lg == 0) {
#pragma unroll
      for (int i = 0; i < 8; i++) {
        int rs = rh * 32 + (i >> 2) * 16 + lh * 4 + (i & 3);
        pmax[kg][rs] = mx[i];
      }
    }
    __syncthreads();                        // b1: pmax complete
    if (tid < 64) {
      float tm = fmaxf(fmaxf(pmax[0][tid], pmax[1][tid]), fmaxf(pmax[2][tid], pmax[3][tid]));
      float mo = mrun[tid];
      float mn = fmaxf(mo, tm);
      mnew_s[tid] = mn;
      fact_s[tid] = exp2f((mo - mn) * LOG2E);
    }
    __syncthreads();                        // b1.5: mnew/fact ready
    // ---- P = exp(S - m_new), partial sums, O-rescale ----
#pragma unroll
    for (int m = 0; m < 2; m++)
#pragma unroll
      for (int r = 0; r < 4; r++) {
        const int rs = rh * 32 + m * 16 + lh * 4 + r;
        const float mn = mnew_s[rs];
        float s0v = m ? s10[r] : s00[r];
        float s1v = m ? s11[r] : s01[r];
        float p0 = exp2f((s0v - mn) * LOG2E);
        float p1 = exp2f((s1v - mn) * LOG2E);
        Ps[rs * 136 + kg * 32 + lg] = bf16r(p0);
        Ps[rs * 136 + kg * 32 + 16 + lg] = bf16r(p1);
        float ps = p0 + p1;
#pragma unroll
        for (int msk = 1; msk < 16; msk <<= 1) ps += __shfl_xor(ps, msk);
        if (lg == 0) psum[kg][rs] = ps;
      }
#pragma unroll
    for (int m4 = 0; m4 < 4; m4++)
#pragma unroll
      for (int r = 0; r < 4; r++) {
        const float f = fact_s[m4 * 16 + lh * 4 + r];
#pragma unroll
        for (int n = 0; n < 4; n++) acc_o[m4][n][r] *= f;
      }
    __syncthreads();                        // b2: Ps/psum complete
    // ---- PV: O[64][w*64..] += P[64][128] * V[128][cols] ----
#pragma unroll
    for (int kk = 0; kk < 4; kk++) {
      bf16x8 pf[4];
#pragma unroll
      for (int m4 = 0; m4 < 4; m4++)
        pf[m4] = *(const bf16x8*)&Ps[(m4 * 16 + lg) * 136 + kk * 32 + lh * 8];
#pragma unroll
      for (int n = 0; n < 4; n++) {
        bf16x8 vf = *(const bf16x8*)&Vg[(long)(w * 64 + n * 16 + lg) * 2048 + k0 + kk * 32 + lh * 8];
#pragma unroll
        for (int m4 = 0; m4 < 4; m4++)
          acc_o[m4][n] = __builtin_amdgcn_mfma_f32_16x16x32_bf16(pf[m4], vf, acc_o[m4][n], 0, 0, 0);
      }
    }
    if (tid < 64) {
      lrun[tid] = lrun[tid] * fact_s[tid] + psum[0][tid] + psum[1][tid] + psum[2][tid] + psum[3][tid];
      mrun[tid] = mnew_s[tid];
    }
  }
  __syncthreads();
  unsigned short* Og = o_lat + ((long)b * 32768 + row0) * 512;
#pragma unroll
  for (int m4 = 0; m4 < 4; m4++)
#pragma unroll
    for (int r = 0; r < 4; r++) {
      const int ro = m4 * 16 + lh * 4 + r;
      const float inv = 1.f / lrun[ro];
#pragma unroll
      for (int n = 0; n < 4; n++)
        Og[(long)ro * 512 + w * 64 + n * 16 + lg] = bf16r(acc_o[m4][n][r] * inv);
    }
}

// ---------- host launcher ----------
extern "C" void kernel_launch(void* const* d_in, const int* in_sizes, int n_in,
                              void* d_out, int out_size, void* d_ws, size_t ws_size,
                              hipStream_t stream) {
  const float* x = (const float*)d_in[0];
  const float* fc = (const float*)d_in[1];
  const float* fs = (const float*)d_in[2];
  const float* wq = (const float*)d_in[3];
  const float* wkva = (const float*)d_in[4];
  const float* wkvb = (const float*)d_in[5];
  const float* wo = (const float*)d_in[6];
  const float* alpha = (const float*)d_in[7];
  const float* gamma = (const float*)d_in[8];
  const float* beta = (const float*)d_in[9];
  float* out = (float*)d_out;

  char* p = (char*)d_ws;
  auto take = [&](size_t bytes) {
    char* r = p;
    p += (bytes + 255) & ~(size_t)255;
    return r;
  };
  unsigned short* xb    = (unsigned short*)take(8388608ull * 2);    // x bf16 [4096][2048]
  unsigned short* wqb   = (unsigned short*)take(6291456ull * 2);    // wq bf16 [3072][2048]
  unsigned short* wab   = (unsigned short*)take(1310720ull * 2);    // wkv_a bf16 padded [640][2048]
  unsigned short* wkT   = (unsigned short*)take(1048576ull * 2);    // [16][512][128]
  unsigned short* wbb   = (unsigned short*)take(2097152ull * 2);    // wkv_b bf16 [4096][512]
  unsigned short* wob   = (unsigned short*)take(4194304ull * 2);    // wo bf16 [2048][2048]
  unsigned short* q_b   = (unsigned short*)take(12582912ull * 2);   // q bf16 [4096][3072]
  float*          kvf   = (float*)take(2359296ull * 4);             // kv_full f32 [4096][576]
  unsigned short* k_lat = (unsigned short*)take(2359296ull * 2);    // [B][2048][576]
  unsigned short* vt    = (unsigned short*)take(2097152ull * 2);    // [B][512][2048]
  unsigned short* q_lat = (unsigned short*)take(37748736ull * 2);   // [B][32768][576]
  unsigned short* o_lat = (unsigned short*)take(33554432ull * 2);   // [B][32768][512]
  unsigned short* o_b   = (unsigned short*)take(8388608ull * 2);    // [4096][2048]

  const float scale = 1.0f / sqrtf(192.0f);

  // conversions
  convk<<<8192, 256, 0, stream>>>(x, xb, 8388608L);
  convk<<<6144, 256, 0, stream>>>(wq, wqb, 6291456L);
  conv_wab<<<1280, 256, 0, stream>>>(wkva, wab);
  make_wkT<<<4096, 256, 0, stream>>>(wkvb, wkT);
  convk<<<2048, 256, 0, stream>>>(wkvb, wbb, 2097152L);
  convk<<<4096, 256, 0, stream>>>(wo, wob, 4194304L);

  // q = x @ wq^T  (bf16 out)
  gemm_bt<1><<<dim3(32, 24, 1), 256, 0, stream>>>(xb, wqb, q_b, 4096, 3072, 2048,
                                                  2048, 2048, 3072, 0, 0, 0, 1.0f);
  // kv_full = x @ wkv_a^T (f32 out, N bounded to 576)
  gemm_bt<0><<<dim3(32, 5, 1), 256, 0, stream>>>(xb, wab, kvf, 4096, 576, 2048,
                                                 2048, 2048, 576, 0, 0, 0, 1.0f);
  // kvn + k_pe rope -> k_lat
  kv_epilogue<<<4096, 256, 0, stream>>>(kvf, fc, fs, alpha, gamma, beta, k_lat);
  // vt = kvn^T
  transpose_v<<<dim3(64, 16, 2), dim3(32, 8), 0, stream>>>(k_lat, vt);
  // q_abs = q_nope @ wk^T per head (scaled), into q_lat[..][0..512)
  gemm_bt<1><<<dim3(32, 4, 16), 256, 0, stream>>>(q_b, wkT, q_lat, 4096, 512, 128,
                                                  3072, 128, 9216, 192, 65536, 576, scale);
  // q_pe rope (scaled) -> q_lat[..][512..576)
  q_rope<<<8192, 256, 0, stream>>>(q_b, fc, fs, q_lat, scale);
  // attention
  attn_kernel<<<1024, 512, 0, stream>>>(q_lat, k_lat, vt, o_lat);
  // o = o_lat @ wv^T per head
  gemm_bt<1><<<dim3(32, 1, 16), 256, 0, stream>>>(o_lat, wbb + 128 * 512, o_b, 4096, 128, 512,
                                                  8192, 512, 2048, 512, 131072, 128, 1.0f);
  // out = o @ wo^T (f32 to d_out)
  gemm_bt<0><<<dim3(32, 16, 1), 256, 0, stream>>>(o_b, wob, out, 4096, 2048, 2048,
                                                  2048, 2048, 2048, 0, 0, 0, 1.0f);
}